// Round 1
// baseline (924.367 us; speedup 1.0000x reference)
//
#include <hip/hip_runtime.h>
#include <math.h>

// ---------------------------------------------------------------------------
// Problem constants (from reference): M=30000 nodes, S=8 cells, D=32 channels,
// DEPTH_LIMIT=10, H=64 hidden, L=7M+1 leaves. Sizes are still taken from
// in_sizes at launch for robustness.
// ---------------------------------------------------------------------------

// Kernel 0: transpose conv_w [d][o][i][k] -> Wt [d][k][i][o]  (o innermost for
// coalesced per-lane reads), and zero the feats accumulator.
__global__ __launch_bounds__(256) void prep_kernel(
    const float* __restrict__ conv_w, float* __restrict__ Wt,
    float* __restrict__ feats, int total /*81920*/)
{
    int tid = blockIdx.x * 256 + threadIdx.x;
    if (tid < total) {
        int o = tid & 31;
        int i = (tid >> 5) & 31;
        int k = (tid >> 10) & 7;
        int d = tid >> 13;
        Wt[tid] = conv_w[((d * 32 + o) * 32 + i) * 8 + k];
    } else if (tid < total + 32) {
        feats[tid - total] = 0.0f;
    }
}

// Kernel 1: one wave (64 threads, one block) per run of equal parent p in
// idx_sorted. Sequential steps within the run, incremental T update.
// Lane layout: og = (l&7)*4 -> 4 output channels, kg = l>>3 -> k-slice.
__global__ __launch_bounds__(64) void conv_scan(
    const float* __restrict__ data, const float* __restrict__ Wt,
    const float* __restrict__ conv_b, const float* __restrict__ depth_weight,
    const int* __restrict__ idx_sorted, const int* __restrict__ depth_sorted,
    const int* __restrict__ node_depth,
    float* __restrict__ pfeats, float* __restrict__ patch, int M)
{
    int t0 = blockIdx.x;
    int p = idx_sorted[t0] >> 3;
    if (t0 > 0 && (idx_sorted[t0 - 1] >> 3) == p) return;  // not a run start

    int n = 1;
    while (t0 + n < M && (idx_sorted[t0 + n] >> 3) == p) n++;

    int cd = node_depth[p];
    const float* __restrict__ W = Wt + cd * 8192;  // [k][i][o]

    __shared__ float blk[8 * 33];   // padded rows: bank = (k + i) % 32, no 8-way conflict
    __shared__ float ubuf[32];

    int l  = threadIdx.x;
    int og = (l & 7) * 4;
    int kg = l >> 3;

    // stage block: lane l loads data[p*256 + l*4 .. +3] -> row kg, cols og..og+3
    {
        const float4 v = *(const float4*)(data + p * 256 + l * 4);
        int base = kg * 33 + og;
        blk[base + 0] = v.x; blk[base + 1] = v.y;
        blk[base + 2] = v.z; blk[base + 3] = v.w;
    }
    __syncthreads();

    // full matvec over this lane's k-slice
    float4 T = {0.f, 0.f, 0.f, 0.f};
    #pragma unroll
    for (int i = 0; i < 32; ++i) {
        float x = blk[kg * 33 + i];
        const float4 w = *(const float4*)(W + (kg * 32 + i) * 32 + og);
        T.x = fmaf(w.x, x, T.x); T.y = fmaf(w.y, x, T.y);
        T.z = fmaf(w.z, x, T.z); T.w = fmaf(w.w, x, T.w);
    }
    // reduce across the 8 kg groups (lane bits 3..5)
    #pragma unroll
    for (int m = 8; m <= 32; m <<= 1) {
        T.x += __shfl_xor(T.x, m, 64);
        T.y += __shfl_xor(T.y, m, 64);
        T.z += __shfl_xor(T.z, m, 64);
        T.w += __shfl_xor(T.w, m, 64);
    }

    const float4 bias = *(const float4*)(conv_b + cd * 32 + og);
    float4 pf = {0.f, 0.f, 0.f, 0.f};

    for (int s = 0;; ++s) {
        int   c  = idx_sorted[t0 + s] & 7;
        float dw = depth_weight[depth_sorted[t0 + s]];
        float4 feat = {T.x + bias.x, T.y + bias.y, T.z + bias.z, T.w + bias.w};
        pf.x = fmaf(dw, feat.x, pf.x); pf.y = fmaf(dw, feat.y, pf.y);
        pf.z = fmaf(dw, feat.z, pf.z); pf.w = fmaf(dw, feat.w, pf.w);

        if (s + 1 == n) {
            // last step of the p==0 run always has c==0 (idx 0 is the global
            // minimum): final value of flat row 0, needed if cell (0,0) is a leaf.
            if (p == 0 && c == 0 && l < 8) {
                *(float4*)(patch + og) = feat;
            }
            break;
        }

        int rb = c * 33 + og;
        float4 oldv = {blk[rb], blk[rb + 1], blk[rb + 2], blk[rb + 3]};
        __syncthreads();
        if (l < 8) {
            blk[rb + 0] = feat.x; blk[rb + 1] = feat.y;
            blk[rb + 2] = feat.z; blk[rb + 3] = feat.w;
            ubuf[og + 0] = feat.x - oldv.x; ubuf[og + 1] = feat.y - oldv.y;
            ubuf[og + 2] = feat.z - oldv.z; ubuf[og + 3] = feat.w - oldv.w;
        }
        __syncthreads();

        // incremental update: T += W[c-slice] . u  (all kg groups redundantly)
        float4 acc = {0.f, 0.f, 0.f, 0.f};
        #pragma unroll
        for (int i = 0; i < 32; ++i) {
            float x = ubuf[i];
            const float4 w = *(const float4*)(W + (c * 32 + i) * 32 + og);
            acc.x = fmaf(w.x, x, acc.x); acc.y = fmaf(w.y, x, acc.y);
            acc.z = fmaf(w.z, x, acc.z); acc.w = fmaf(w.w, x, acc.w);
        }
        T.x += acc.x; T.y += acc.y; T.z += acc.z; T.w += acc.w;
    }

    if (l < 8) *(float4*)(pfeats + t0 * 32 + og) = pf;
}

// Kernel 2: sum the per-run partial feats rows (valid only at run starts).
__global__ __launch_bounds__(1024) void reduce_feats(
    const int* __restrict__ idx_sorted, const float* __restrict__ pfeats,
    float* __restrict__ feats, int M)
{
    int ch  = threadIdx.x & 31;
    int sub = threadIdx.x >> 5;  // 0..31
    int base = blockIdx.x * 1000;
    int end  = base + 1000; if (end > M) end = M;

    float a = 0.f;
    for (int t = base + sub; t < end; t += 32) {
        int p = idx_sorted[t] >> 3;
        bool start = (t == 0) || ((idx_sorted[t - 1] >> 3) != p);
        if (start) a += pfeats[t * 32 + ch];
    }
    __shared__ float red[1024];
    red[sub * 32 + ch] = a;
    __syncthreads();
    #pragma unroll
    for (int h = 16; h > 0; h >>= 1) {
        if (sub < h) red[sub * 32 + ch] += red[(sub + h) * 32 + ch];
        __syncthreads();
    }
    if (sub == 0) atomicAdd(&feats[ch], red[ch]);
}

// Kernel 3: leaf gather + two GELU MLPs (fp32), one leaf per thread.
__global__ __launch_bounds__(256) void mlp_kernel(
    const float* __restrict__ data, const float* __restrict__ feats,
    const float* __restrict__ patch, const int* __restrict__ leaf_idx,
    const float* __restrict__ hf_w1, const float* __restrict__ hf_b1,
    const float* __restrict__ hf_w2, const float* __restrict__ hf_b2,
    const float* __restrict__ hs_w1, const float* __restrict__ hs_b1,
    const float* __restrict__ hs_w2, const float* __restrict__ hs_b2,
    float* __restrict__ out, int L)
{
    __shared__ __align__(16) float w1f[2048];
    __shared__ __align__(16) float w1s[2048];
    __shared__ float w2f[192];
    __shared__ float w2s[64];
    __shared__ float b1f[64], b1s[64], fts[32], pat[32];
    __shared__ float b2f[4];

    for (int j = threadIdx.x; j < 2048; j += 256) {
        w1f[j] = hf_w1[j];
        w1s[j] = hs_w1[j];
    }
    if (threadIdx.x < 192) w2f[threadIdx.x] = hf_w2[threadIdx.x];
    if (threadIdx.x < 64) {
        w2s[threadIdx.x] = hs_w2[threadIdx.x];
        b1f[threadIdx.x] = hf_b1[threadIdx.x];
        b1s[threadIdx.x] = hs_b1[threadIdx.x];
    }
    if (threadIdx.x < 32) {
        fts[threadIdx.x] = feats[threadIdx.x];
        pat[threadIdx.x] = patch[threadIdx.x];
    }
    if (threadIdx.x < 3) b2f[threadIdx.x] = hf_b2[threadIdx.x];
    if (threadIdx.x == 3) b2f[3] = hs_b2[0];
    __syncthreads();

    int r = blockIdx.x * 256 + threadIdx.x;
    if (r >= L) return;
    int row = leaf_idx[r];

    float g[32];
    if (row != 0) {
        const float4* dp = (const float4*)(data + (size_t)row * 32);
        #pragma unroll
        for (int q = 0; q < 8; ++q) {
            float4 v = dp[q];
            g[q * 4 + 0] = v.x + fts[q * 4 + 0];
            g[q * 4 + 1] = v.y + fts[q * 4 + 1];
            g[q * 4 + 2] = v.z + fts[q * 4 + 2];
            g[q * 4 + 3] = v.w + fts[q * 4 + 3];
        }
    } else {
        #pragma unroll
        for (int i = 0; i < 32; ++i) g[i] = pat[i] + fts[i];
    }

    float o0 = b2f[0], o1 = b2f[1], o2 = b2f[2], o3 = b2f[3];

    // f-MLP: 32 -> 64 -> GELU(erf) -> 3, processed in 4 chunks of 16 hidden
    #pragma unroll
    for (int cb = 0; cb < 64; cb += 16) {
        float acc[16];
        #pragma unroll
        for (int j = 0; j < 16; ++j) acc[j] = b1f[cb + j];
        #pragma unroll
        for (int i = 0; i < 32; ++i) {
            float gi = g[i];
            #pragma unroll
            for (int j4 = 0; j4 < 16; j4 += 4) {
                const float4 w = *(const float4*)(w1f + i * 64 + cb + j4);
                acc[j4 + 0] = fmaf(gi, w.x, acc[j4 + 0]);
                acc[j4 + 1] = fmaf(gi, w.y, acc[j4 + 1]);
                acc[j4 + 2] = fmaf(gi, w.z, acc[j4 + 2]);
                acc[j4 + 3] = fmaf(gi, w.w, acc[j4 + 3]);
            }
        }
        #pragma unroll
        for (int j = 0; j < 16; ++j) {
            float x  = acc[j];
            float ge = 0.5f * x * (1.0f + erff(x * 0.70710678118654752f));
            int hh = cb + j;
            o0 = fmaf(ge, w2f[hh * 3 + 0], o0);
            o1 = fmaf(ge, w2f[hh * 3 + 1], o1);
            o2 = fmaf(ge, w2f[hh * 3 + 2], o2);
        }
    }

    // sigma-MLP: 32 -> 64 -> GELU(erf) -> 1
    #pragma unroll
    for (int cb = 0; cb < 64; cb += 16) {
        float acc[16];
        #pragma unroll
        for (int j = 0; j < 16; ++j) acc[j] = b1s[cb + j];
        #pragma unroll
        for (int i = 0; i < 32; ++i) {
            float gi = g[i];
            #pragma unroll
            for (int j4 = 0; j4 < 16; j4 += 4) {
                const float4 w = *(const float4*)(w1s + i * 64 + cb + j4);
                acc[j4 + 0] = fmaf(gi, w.x, acc[j4 + 0]);
                acc[j4 + 1] = fmaf(gi, w.y, acc[j4 + 1]);
                acc[j4 + 2] = fmaf(gi, w.z, acc[j4 + 2]);
                acc[j4 + 3] = fmaf(gi, w.w, acc[j4 + 3]);
            }
        }
        #pragma unroll
        for (int j = 0; j < 16; ++j) {
            float x  = acc[j];
            float ge = 0.5f * x * (1.0f + erff(x * 0.70710678118654752f));
            o3 = fmaf(ge, w2s[cb + j], o3);
        }
    }

    float4 res = {o0, o1, o2, o3};
    *(float4*)(out + (size_t)r * 4) = res;
}

extern "C" void kernel_launch(void* const* d_in, const int* in_sizes, int n_in,
                              void* d_out, int out_size, void* d_ws, size_t ws_size,
                              hipStream_t stream)
{
    const float* data         = (const float*)d_in[0];
    const float* conv_w       = (const float*)d_in[1];
    const float* conv_b       = (const float*)d_in[2];
    const float* depth_weight = (const float*)d_in[3];
    const float* hf_w1        = (const float*)d_in[4];
    const float* hf_b1        = (const float*)d_in[5];
    const float* hf_w2        = (const float*)d_in[6];
    const float* hf_b2        = (const float*)d_in[7];
    const float* hs_w1        = (const float*)d_in[8];
    const float* hs_b1        = (const float*)d_in[9];
    const float* hs_w2        = (const float*)d_in[10];
    const float* hs_b2        = (const float*)d_in[11];
    const int*   idx_sorted   = (const int*)d_in[12];
    const int*   depth_sorted = (const int*)d_in[13];
    const int*   node_depth   = (const int*)d_in[14];
    const int*   leaf_idx     = (const int*)d_in[15];

    int M = in_sizes[12];   // 30000
    int L = in_sizes[15];   // 210001
    float* out = (float*)d_out;

    // workspace layout (floats): Wt[81920] | feats[32] | patch[32] | pfeats[M*32]
    float* Wt     = (float*)d_ws;
    float* feats  = Wt + 81920;
    float* patch  = feats + 32;
    float* pfeats = patch + 32;
    const int WT = 81920;

    prep_kernel<<<(WT + 32 + 255) / 256, 256, 0, stream>>>(conv_w, Wt, feats, WT);
    conv_scan<<<M, 64, 0, stream>>>(data, Wt, conv_b, depth_weight,
                                    idx_sorted, depth_sorted, node_depth,
                                    pfeats, patch, M);
    reduce_feats<<<(M + 999) / 1000, 1024, 0, stream>>>(idx_sorted, pfeats, feats, M);
    mlp_kernel<<<(L + 255) / 256, 256, 0, stream>>>(data, feats, patch, leaf_idx,
                                                    hf_w1, hf_b1, hf_w2, hf_b2,
                                                    hs_w1, hs_b1, hs_w2, hs_b2,
                                                    out, L);
}

// Round 2
// 304.665 us; speedup vs baseline: 3.0340x; 3.0340x over previous
//
#include <hip/hip_runtime.h>
#include <math.h>

// ---------------------------------------------------------------------------
// Problem constants (from reference): M=30000 nodes, S=8 cells, D=32 channels,
// DEPTH_LIMIT=10, H=64 hidden, L=7M+1 leaves. Sizes are still taken from
// in_sizes at launch for robustness.
// ---------------------------------------------------------------------------

// Kernel 0: transpose conv_w [d][o][i][k] -> Wt [d][k][i][o]  (o innermost for
// coalesced per-lane reads), and zero the feats accumulator.
__global__ __launch_bounds__(256) void prep_kernel(
    const float* __restrict__ conv_w, float* __restrict__ Wt,
    float* __restrict__ feats, int total /*81920*/)
{
    int tid = blockIdx.x * 256 + threadIdx.x;
    if (tid < total) {
        int o = tid & 31;
        int i = (tid >> 5) & 31;
        int k = (tid >> 10) & 7;
        int d = tid >> 13;
        Wt[tid] = conv_w[((d * 32 + o) * 32 + i) * 8 + k];
    } else if (tid < total + 32) {
        feats[tid - total] = 0.0f;
    }
}

// Kernel 1: one wave (64 threads, one block) per run of equal parent p in
// idx_sorted. Sequential steps within the run, incremental T update.
// Lane layout: og = (l&7)*4 -> 4 output channels, kg = l>>3 -> k-slice.
__global__ __launch_bounds__(64) void conv_scan(
    const float* __restrict__ data, const float* __restrict__ Wt,
    const float* __restrict__ conv_b, const float* __restrict__ depth_weight,
    const int* __restrict__ idx_sorted, const int* __restrict__ depth_sorted,
    const int* __restrict__ node_depth,
    float* __restrict__ pfeats, float* __restrict__ patch, int M)
{
    int t0 = blockIdx.x;
    int p = idx_sorted[t0] >> 3;
    if (t0 > 0 && (idx_sorted[t0 - 1] >> 3) == p) return;  // not a run start

    int n = 1;
    while (t0 + n < M && (idx_sorted[t0 + n] >> 3) == p) n++;

    int cd = node_depth[p];
    const float* __restrict__ W = Wt + cd * 8192;  // [k][i][o]

    __shared__ float blk[8 * 33];   // padded rows
    __shared__ float ubuf[32];

    int l  = threadIdx.x;
    int og = (l & 7) * 4;
    int kg = l >> 3;

    // stage block: lane l loads data[p*256 + l*4 .. +3] -> row kg, cols og..og+3
    {
        const float4 v = *(const float4*)(data + p * 256 + l * 4);
        int base = kg * 33 + og;
        blk[base + 0] = v.x; blk[base + 1] = v.y;
        blk[base + 2] = v.z; blk[base + 3] = v.w;
    }
    __syncthreads();

    // full matvec over this lane's k-slice
    float4 T = {0.f, 0.f, 0.f, 0.f};
    #pragma unroll
    for (int i = 0; i < 32; ++i) {
        float x = blk[kg * 33 + i];
        const float4 w = *(const float4*)(W + (kg * 32 + i) * 32 + og);
        T.x = fmaf(w.x, x, T.x); T.y = fmaf(w.y, x, T.y);
        T.z = fmaf(w.z, x, T.z); T.w = fmaf(w.w, x, T.w);
    }
    // reduce across the 8 kg groups (lane bits 3..5)
    #pragma unroll
    for (int m = 8; m <= 32; m <<= 1) {
        T.x += __shfl_xor(T.x, m, 64);
        T.y += __shfl_xor(T.y, m, 64);
        T.z += __shfl_xor(T.z, m, 64);
        T.w += __shfl_xor(T.w, m, 64);
    }

    const float4 bias = *(const float4*)(conv_b + cd * 32 + og);
    float4 pf = {0.f, 0.f, 0.f, 0.f};

    for (int s = 0;; ++s) {
        int   c  = idx_sorted[t0 + s] & 7;
        float dw = depth_weight[depth_sorted[t0 + s]];
        float4 feat = {T.x + bias.x, T.y + bias.y, T.z + bias.z, T.w + bias.w};
        pf.x = fmaf(dw, feat.x, pf.x); pf.y = fmaf(dw, feat.y, pf.y);
        pf.z = fmaf(dw, feat.z, pf.z); pf.w = fmaf(dw, feat.w, pf.w);

        if (s + 1 == n) {
            // last step of the p==0 run always has c==0: final value of flat
            // row 0, needed if cell (0,0) is a leaf.
            if (p == 0 && c == 0 && l < 8) {
                *(float4*)(patch + og) = feat;
            }
            break;
        }

        int rb = c * 33 + og;
        float4 oldv = {blk[rb], blk[rb + 1], blk[rb + 2], blk[rb + 3]};
        __syncthreads();
        if (l < 8) {
            blk[rb + 0] = feat.x; blk[rb + 1] = feat.y;
            blk[rb + 2] = feat.z; blk[rb + 3] = feat.w;
            ubuf[og + 0] = feat.x - oldv.x; ubuf[og + 1] = feat.y - oldv.y;
            ubuf[og + 2] = feat.z - oldv.z; ubuf[og + 3] = feat.w - oldv.w;
        }
        __syncthreads();

        // incremental update: T += W[c-slice] . u  (all kg groups redundantly)
        float4 acc = {0.f, 0.f, 0.f, 0.f};
        #pragma unroll
        for (int i = 0; i < 32; ++i) {
            float x = ubuf[i];
            const float4 w = *(const float4*)(W + (c * 32 + i) * 32 + og);
            acc.x = fmaf(w.x, x, acc.x); acc.y = fmaf(w.y, x, acc.y);
            acc.z = fmaf(w.z, x, acc.z); acc.w = fmaf(w.w, x, acc.w);
        }
        T.x += acc.x; T.y += acc.y; T.z += acc.z; T.w += acc.w;
    }

    if (l < 8) *(float4*)(pfeats + t0 * 32 + og) = pf;
}

// Kernel 2: sum the per-run partial feats rows (valid only at run starts).
__global__ __launch_bounds__(1024) void reduce_feats(
    const int* __restrict__ idx_sorted, const float* __restrict__ pfeats,
    float* __restrict__ feats, int M)
{
    int ch  = threadIdx.x & 31;
    int sub = threadIdx.x >> 5;  // 0..31
    int base = blockIdx.x * 1000;
    int end  = base + 1000; if (end > M) end = M;

    float a = 0.f;
    for (int t = base + sub; t < end; t += 32) {
        int p = idx_sorted[t] >> 3;
        bool start = (t == 0) || ((idx_sorted[t - 1] >> 3) != p);
        if (start) a += pfeats[t * 32 + ch];
    }
    __shared__ float red[1024];
    red[sub * 32 + ch] = a;
    __syncthreads();
    #pragma unroll
    for (int h = 16; h > 0; h >>= 1) {
        if (sub < h) red[sub * 32 + ch] += red[(sub + h) * 32 + ch];
        __syncthreads();
    }
    if (sub == 0) atomicAdd(&feats[ch], red[ch]);
}

// Inline erf-GELU: Abramowitz-Stegun 7.1.26 (|erf err| <= 1.5e-7), no libm
// call -> no ABI spill pressure. Uses native rcp + exp.
__device__ __forceinline__ float gelu_erf(float x)
{
    const float s  = x * 0.70710678118654752f;   // x / sqrt(2)
    const float ax = fabsf(s);
    const float t  = __builtin_amdgcn_rcpf(fmaf(0.3275911f, ax, 1.0f));
    float poly = fmaf(1.061405429f, t, -1.453152027f);
    poly = fmaf(poly, t, 1.421413741f);
    poly = fmaf(poly, t, -0.284496736f);
    poly = fmaf(poly, t, 0.254829592f);
    poly *= t;
    const float e  = __expf(-s * s);
    float er = fmaf(-poly, e, 1.0f);
    er = copysignf(er, s);
    return 0.5f * x * (1.0f + er);
}

// Kernel 3: leaf gather + two GELU MLPs (fp32), one leaf per thread.
__global__ __launch_bounds__(256) void mlp_kernel(
    const float* __restrict__ data, const float* __restrict__ feats,
    const float* __restrict__ patch, const int* __restrict__ leaf_idx,
    const float* __restrict__ hf_w1, const float* __restrict__ hf_b1,
    const float* __restrict__ hf_w2, const float* __restrict__ hf_b2,
    const float* __restrict__ hs_w1, const float* __restrict__ hs_b1,
    const float* __restrict__ hs_w2, const float* __restrict__ hs_b2,
    float* __restrict__ out, int L)
{
    __shared__ __align__(16) float w1f[2048];
    __shared__ __align__(16) float w1s[2048];
    __shared__ float w2f[192];
    __shared__ float w2s[64];
    __shared__ float b1f[64], b1s[64], fts[32], pat[32];
    __shared__ float b2f[4];

    for (int j = threadIdx.x; j < 2048; j += 256) {
        w1f[j] = hf_w1[j];
        w1s[j] = hs_w1[j];
    }
    if (threadIdx.x < 192) w2f[threadIdx.x] = hf_w2[threadIdx.x];
    if (threadIdx.x < 64) {
        w2s[threadIdx.x] = hs_w2[threadIdx.x];
        b1f[threadIdx.x] = hf_b1[threadIdx.x];
        b1s[threadIdx.x] = hs_b1[threadIdx.x];
    }
    if (threadIdx.x < 32) {
        fts[threadIdx.x] = feats[threadIdx.x];
        pat[threadIdx.x] = patch[threadIdx.x];
    }
    if (threadIdx.x < 3) b2f[threadIdx.x] = hf_b2[threadIdx.x];
    if (threadIdx.x == 3) b2f[3] = hs_b2[0];
    __syncthreads();

    int r = blockIdx.x * 256 + threadIdx.x;
    if (r >= L) return;
    int row = leaf_idx[r];

    float g[32];
    if (row != 0) {
        const float4* dp = (const float4*)(data + (size_t)row * 32);
        #pragma unroll
        for (int q = 0; q < 8; ++q) {
            float4 v = dp[q];
            g[q * 4 + 0] = v.x + fts[q * 4 + 0];
            g[q * 4 + 1] = v.y + fts[q * 4 + 1];
            g[q * 4 + 2] = v.z + fts[q * 4 + 2];
            g[q * 4 + 3] = v.w + fts[q * 4 + 3];
        }
    } else {
        #pragma unroll
        for (int i = 0; i < 32; ++i) g[i] = pat[i] + fts[i];
    }

    float o0 = b2f[0], o1 = b2f[1], o2 = b2f[2], o3 = b2f[3];

    // f-MLP: 32 -> 64 -> GELU(erf) -> 3, processed in 4 chunks of 16 hidden
    #pragma unroll
    for (int cb = 0; cb < 64; cb += 16) {
        float acc[16];
        #pragma unroll
        for (int j = 0; j < 16; ++j) acc[j] = b1f[cb + j];
        #pragma unroll
        for (int i = 0; i < 32; ++i) {
            float gi = g[i];
            #pragma unroll
            for (int j4 = 0; j4 < 16; j4 += 4) {
                const float4 w = *(const float4*)(w1f + i * 64 + cb + j4);
                acc[j4 + 0] = fmaf(gi, w.x, acc[j4 + 0]);
                acc[j4 + 1] = fmaf(gi, w.y, acc[j4 + 1]);
                acc[j4 + 2] = fmaf(gi, w.z, acc[j4 + 2]);
                acc[j4 + 3] = fmaf(gi, w.w, acc[j4 + 3]);
            }
        }
        #pragma unroll
        for (int j = 0; j < 16; ++j) {
            float ge = gelu_erf(acc[j]);
            int hh = cb + j;
            o0 = fmaf(ge, w2f[hh * 3 + 0], o0);
            o1 = fmaf(ge, w2f[hh * 3 + 1], o1);
            o2 = fmaf(ge, w2f[hh * 3 + 2], o2);
        }
    }

    // sigma-MLP: 32 -> 64 -> GELU(erf) -> 1
    #pragma unroll
    for (int cb = 0; cb < 64; cb += 16) {
        float acc[16];
        #pragma unroll
        for (int j = 0; j < 16; ++j) acc[j] = b1s[cb + j];
        #pragma unroll
        for (int i = 0; i < 32; ++i) {
            float gi = g[i];
            #pragma unroll
            for (int j4 = 0; j4 < 16; j4 += 4) {
                const float4 w = *(const float4*)(w1s + i * 64 + cb + j4);
                acc[j4 + 0] = fmaf(gi, w.x, acc[j4 + 0]);
                acc[j4 + 1] = fmaf(gi, w.y, acc[j4 + 1]);
                acc[j4 + 2] = fmaf(gi, w.z, acc[j4 + 2]);
                acc[j4 + 3] = fmaf(gi, w.w, acc[j4 + 3]);
            }
        }
        #pragma unroll
        for (int j = 0; j < 16; ++j) {
            float ge = gelu_erf(acc[j]);
            o3 = fmaf(ge, w2s[cb + j], o3);
        }
    }

    float4 res = {o0, o1, o2, o3};
    *(float4*)(out + (size_t)r * 4) = res;
}

extern "C" void kernel_launch(void* const* d_in, const int* in_sizes, int n_in,
                              void* d_out, int out_size, void* d_ws, size_t ws_size,
                              hipStream_t stream)
{
    const float* data         = (const float*)d_in[0];
    const float* conv_w       = (const float*)d_in[1];
    const float* conv_b       = (const float*)d_in[2];
    const float* depth_weight = (const float*)d_in[3];
    const float* hf_w1        = (const float*)d_in[4];
    const float* hf_b1        = (const float*)d_in[5];
    const float* hf_w2        = (const float*)d_in[6];
    const float* hf_b2        = (const float*)d_in[7];
    const float* hs_w1        = (const float*)d_in[8];
    const float* hs_b1        = (const float*)d_in[9];
    const float* hs_w2        = (const float*)d_in[10];
    const float* hs_b2        = (const float*)d_in[11];
    const int*   idx_sorted   = (const int*)d_in[12];
    const int*   depth_sorted = (const int*)d_in[13];
    const int*   node_depth   = (const int*)d_in[14];
    const int*   leaf_idx     = (const int*)d_in[15];

    int M = in_sizes[12];   // 30000
    int L = in_sizes[15];   // 210001
    float* out = (float*)d_out;

    // workspace layout (floats): Wt[81920] | feats[32] | patch[32] | pfeats[M*32]
    float* Wt     = (float*)d_ws;
    float* feats  = Wt + 81920;
    float* patch  = feats + 32;
    float* pfeats = patch + 32;
    const int WT = 81920;

    prep_kernel<<<(WT + 32 + 255) / 256, 256, 0, stream>>>(conv_w, Wt, feats, WT);
    conv_scan<<<M, 64, 0, stream>>>(data, Wt, conv_b, depth_weight,
                                    idx_sorted, depth_sorted, node_depth,
                                    pfeats, patch, M);
    reduce_feats<<<(M + 999) / 1000, 1024, 0, stream>>>(idx_sorted, pfeats, feats, M);
    mlp_kernel<<<(L + 255) / 256, 256, 0, stream>>>(data, feats, patch, leaf_idx,
                                                    hf_w1, hf_b1, hf_w2, hf_b2,
                                                    hs_w1, hs_b1, hs_w2, hs_b2,
                                                    out, L);
}

// Round 3
// 158.135 us; speedup vs baseline: 5.8454x; 1.9266x over previous
//
#include <hip/hip_runtime.h>
#include <math.h>

// ---------------------------------------------------------------------------
// Problem constants (from reference): M=30000 nodes, S=8 cells, D=32 channels,
// DEPTH_LIMIT=10, H=64 hidden, L=7M+1 leaves.
// ---------------------------------------------------------------------------

// Kernel 0: transpose conv_w [d][o][i][k] -> Wt [d][k][i][o]  (o innermost for
// coalesced per-lane reads), and zero the feats accumulator.
__global__ __launch_bounds__(256) void prep_kernel(
    const float* __restrict__ conv_w, float* __restrict__ Wt,
    float* __restrict__ feats, int total /*81920*/)
{
    int tid = blockIdx.x * 256 + threadIdx.x;
    if (tid < total) {
        int o = tid & 31;
        int i = (tid >> 5) & 31;
        int k = (tid >> 10) & 7;
        int d = tid >> 13;
        Wt[tid] = conv_w[((d * 32 + o) * 32 + i) * 8 + k];
    } else if (tid < total + 32) {
        feats[tid - total] = 0.0f;
    }
}

// Kernel 1: one wave (64 threads, one block) per run of equal parent p in
// idx_sorted. Sequential steps within the run, incremental T update.
// Lane layout: og = (l&7)*4 -> 4 output channels, kg = l>>3 -> k-slice.
__global__ __launch_bounds__(64) void conv_scan(
    const float* __restrict__ data, const float* __restrict__ Wt,
    const float* __restrict__ conv_b, const float* __restrict__ depth_weight,
    const int* __restrict__ idx_sorted, const int* __restrict__ depth_sorted,
    const int* __restrict__ node_depth,
    float* __restrict__ pfeats, float* __restrict__ patch, int M)
{
    int t0 = blockIdx.x;
    int p = idx_sorted[t0] >> 3;
    if (t0 > 0 && (idx_sorted[t0 - 1] >> 3) == p) return;  // not a run start

    int n = 1;
    while (t0 + n < M && (idx_sorted[t0 + n] >> 3) == p) n++;

    int cd = node_depth[p];
    const float* __restrict__ W = Wt + cd * 8192;  // [k][i][o]

    __shared__ float blk[8 * 33];   // padded rows
    __shared__ float ubuf[32];

    int l  = threadIdx.x;
    int og = (l & 7) * 4;
    int kg = l >> 3;

    // stage block: lane l loads data[p*256 + l*4 .. +3] -> row kg, cols og..og+3
    {
        const float4 v = *(const float4*)(data + p * 256 + l * 4);
        int base = kg * 33 + og;
        blk[base + 0] = v.x; blk[base + 1] = v.y;
        blk[base + 2] = v.z; blk[base + 3] = v.w;
    }
    __syncthreads();

    // full matvec over this lane's k-slice
    float4 T = {0.f, 0.f, 0.f, 0.f};
    #pragma unroll
    for (int i = 0; i < 32; ++i) {
        float x = blk[kg * 33 + i];
        const float4 w = *(const float4*)(W + (kg * 32 + i) * 32 + og);
        T.x = fmaf(w.x, x, T.x); T.y = fmaf(w.y, x, T.y);
        T.z = fmaf(w.z, x, T.z); T.w = fmaf(w.w, x, T.w);
    }
    // reduce across the 8 kg groups (lane bits 3..5)
    #pragma unroll
    for (int m = 8; m <= 32; m <<= 1) {
        T.x += __shfl_xor(T.x, m, 64);
        T.y += __shfl_xor(T.y, m, 64);
        T.z += __shfl_xor(T.z, m, 64);
        T.w += __shfl_xor(T.w, m, 64);
    }

    const float4 bias = *(const float4*)(conv_b + cd * 32 + og);
    float4 pf = {0.f, 0.f, 0.f, 0.f};

    for (int s = 0;; ++s) {
        int   c  = idx_sorted[t0 + s] & 7;
        float dw = depth_weight[depth_sorted[t0 + s]];
        float4 feat = {T.x + bias.x, T.y + bias.y, T.z + bias.z, T.w + bias.w};
        pf.x = fmaf(dw, feat.x, pf.x); pf.y = fmaf(dw, feat.y, pf.y);
        pf.z = fmaf(dw, feat.z, pf.z); pf.w = fmaf(dw, feat.w, pf.w);

        if (s + 1 == n) {
            // last step of the p==0 run always has c==0: final value of flat
            // row 0, needed if cell (0,0) is a leaf.
            if (p == 0 && c == 0 && l < 8) {
                *(float4*)(patch + og) = feat;
            }
            break;
        }

        int rb = c * 33 + og;
        float4 oldv = {blk[rb], blk[rb + 1], blk[rb + 2], blk[rb + 3]};
        __syncthreads();
        if (l < 8) {
            blk[rb + 0] = feat.x; blk[rb + 1] = feat.y;
            blk[rb + 2] = feat.z; blk[rb + 3] = feat.w;
            ubuf[og + 0] = feat.x - oldv.x; ubuf[og + 1] = feat.y - oldv.y;
            ubuf[og + 2] = feat.z - oldv.z; ubuf[og + 3] = feat.w - oldv.w;
        }
        __syncthreads();

        // incremental update: T += W[c-slice] . u  (all kg groups redundantly)
        float4 acc = {0.f, 0.f, 0.f, 0.f};
        #pragma unroll
        for (int i = 0; i < 32; ++i) {
            float x = ubuf[i];
            const float4 w = *(const float4*)(W + (c * 32 + i) * 32 + og);
            acc.x = fmaf(w.x, x, acc.x); acc.y = fmaf(w.y, x, acc.y);
            acc.z = fmaf(w.z, x, acc.z); acc.w = fmaf(w.w, x, acc.w);
        }
        T.x += acc.x; T.y += acc.y; T.z += acc.z; T.w += acc.w;
    }

    if (l < 8) *(float4*)(pfeats + t0 * 32 + og) = pf;
}

// Kernel 2: sum the per-run partial feats rows (valid only at run starts).
__global__ __launch_bounds__(1024) void reduce_feats(
    const int* __restrict__ idx_sorted, const float* __restrict__ pfeats,
    float* __restrict__ feats, int M)
{
    int ch  = threadIdx.x & 31;
    int sub = threadIdx.x >> 5;  // 0..31
    int base = blockIdx.x * 1000;
    int end  = base + 1000; if (end > M) end = M;

    float a = 0.f;
    for (int t = base + sub; t < end; t += 32) {
        int p = idx_sorted[t] >> 3;
        bool start = (t == 0) || ((idx_sorted[t - 1] >> 3) != p);
        if (start) a += pfeats[t * 32 + ch];
    }
    __shared__ float red[1024];
    red[sub * 32 + ch] = a;
    __syncthreads();
    #pragma unroll
    for (int h = 16; h > 0; h >>= 1) {
        if (sub < h) red[sub * 32 + ch] += red[(sub + h) * 32 + ch];
        __syncthreads();
    }
    if (sub == 0) atomicAdd(&feats[ch], red[ch]);
}

// Inline erf-GELU: Abramowitz-Stegun 7.1.26 (|erf err| <= 1.5e-7), no libm
// call. Uses native rcp + exp.
__device__ __forceinline__ float gelu_erf(float x)
{
    const float s  = x * 0.70710678118654752f;   // x / sqrt(2)
    const float ax = fabsf(s);
    const float t  = __builtin_amdgcn_rcpf(fmaf(0.3275911f, ax, 1.0f));
    float poly = fmaf(1.061405429f, t, -1.453152027f);
    poly = fmaf(poly, t, 1.421413741f);
    poly = fmaf(poly, t, -0.284496736f);
    poly = fmaf(poly, t, 0.254829592f);
    poly *= t;
    const float e  = __expf(-s * s);
    float er = fmaf(-poly, e, 1.0f);
    er = copysignf(er, s);
    return 0.5f * x * (1.0f + er);
}

// Kernel 3: leaf gather + two GELU MLPs (fp32), one leaf per thread.
// NO LDS: all weight/bias/feats accesses are wave-uniform -> compiler
// scalarizes them to s_load (SMEM pipe), fma reads the SGPR operand directly.
// Per-thread VGPR state: g[32] + acc[16] + out[4] + temps (~70) -> no spill.
__global__ __launch_bounds__(256) void mlp_kernel(
    const float* __restrict__ data, const float* __restrict__ feats,
    const float* __restrict__ patch, const int* __restrict__ leaf_idx,
    const float* __restrict__ hf_w1, const float* __restrict__ hf_b1,
    const float* __restrict__ hf_w2, const float* __restrict__ hf_b2,
    const float* __restrict__ hs_w1, const float* __restrict__ hs_b1,
    const float* __restrict__ hs_w2, const float* __restrict__ hs_b2,
    float* __restrict__ out, int L)
{
    int r = blockIdx.x * 256 + threadIdx.x;
    if (r >= L) return;
    int row = leaf_idx[r];

    // gather g = (row==0 ? patch : data[row]) + feats
    float g[32];
    {
        const float* src = (row == 0) ? patch : (data + (size_t)row * 32);
        #pragma unroll
        for (int q = 0; q < 8; ++q) {
            float4 v = *(const float4*)(src + q * 4);
            g[q * 4 + 0] = v.x + feats[q * 4 + 0];
            g[q * 4 + 1] = v.y + feats[q * 4 + 1];
            g[q * 4 + 2] = v.z + feats[q * 4 + 2];
            g[q * 4 + 3] = v.w + feats[q * 4 + 3];
        }
    }

    float o0 = hf_b2[0], o1 = hf_b2[1], o2 = hf_b2[2], o3 = hs_b2[0];

    // hidden units in chunks of 8, both MLPs together (g[i] feeds 16 fma).
    // unroll 1 on the chunk loop keeps the SGPR/scheduling window bounded.
    #pragma unroll 1
    for (int jc = 0; jc < 64; jc += 8) {
        float accf[8], accs[8];
        #pragma unroll
        for (int j = 0; j < 8; ++j) {
            accf[j] = hf_b1[jc + j];
            accs[j] = hs_b1[jc + j];
        }
        #pragma unroll
        for (int i = 0; i < 32; ++i) {
            float gi = g[i];
            #pragma unroll
            for (int j = 0; j < 8; ++j) {
                accf[j] = fmaf(gi, hf_w1[i * 64 + jc + j], accf[j]);
                accs[j] = fmaf(gi, hs_w1[i * 64 + jc + j], accs[j]);
            }
        }
        #pragma unroll
        for (int j = 0; j < 8; ++j) {
            float gef = gelu_erf(accf[j]);
            float ges = gelu_erf(accs[j]);
            int hh = jc + j;
            o0 = fmaf(gef, hf_w2[hh * 3 + 0], o0);
            o1 = fmaf(gef, hf_w2[hh * 3 + 1], o1);
            o2 = fmaf(gef, hf_w2[hh * 3 + 2], o2);
            o3 = fmaf(ges, hs_w2[hh], o3);
        }
    }

    float4 res = {o0, o1, o2, o3};
    *(float4*)(out + (size_t)r * 4) = res;
}

extern "C" void kernel_launch(void* const* d_in, const int* in_sizes, int n_in,
                              void* d_out, int out_size, void* d_ws, size_t ws_size,
                              hipStream_t stream)
{
    const float* data         = (const float*)d_in[0];
    const float* conv_w       = (const float*)d_in[1];
    const float* conv_b       = (const float*)d_in[2];
    const float* depth_weight = (const float*)d_in[3];
    const float* hf_w1        = (const float*)d_in[4];
    const float* hf_b1        = (const float*)d_in[5];
    const float* hf_w2        = (const float*)d_in[6];
    const float* hf_b2        = (const float*)d_in[7];
    const float* hs_w1        = (const float*)d_in[8];
    const float* hs_b1        = (const float*)d_in[9];
    const float* hs_w2        = (const float*)d_in[10];
    const float* hs_b2        = (const float*)d_in[11];
    const int*   idx_sorted   = (const int*)d_in[12];
    const int*   depth_sorted = (const int*)d_in[13];
    const int*   node_depth   = (const int*)d_in[14];
    const int*   leaf_idx     = (const int*)d_in[15];

    int M = in_sizes[12];   // 30000
    int L = in_sizes[15];   // 210001
    float* out = (float*)d_out;

    // workspace layout (floats): Wt[81920] | feats[32] | patch[32] | pfeats[M*32]
    float* Wt     = (float*)d_ws;
    float* feats  = Wt + 81920;
    float* patch  = feats + 32;
    float* pfeats = patch + 32;
    const int WT = 81920;

    prep_kernel<<<(WT + 32 + 255) / 256, 256, 0, stream>>>(conv_w, Wt, feats, WT);
    conv_scan<<<M, 64, 0, stream>>>(data, Wt, conv_b, depth_weight,
                                    idx_sorted, depth_sorted, node_depth,
                                    pfeats, patch, M);
    reduce_feats<<<(M + 999) / 1000, 1024, 0, stream>>>(idx_sorted, pfeats, feats, M);
    mlp_kernel<<<(L + 255) / 256, 256, 0, stream>>>(data, feats, patch, leaf_idx,
                                                    hf_w1, hf_b1, hf_w2, hf_b2,
                                                    hs_w1, hs_b1, hs_w2, hs_b2,
                                                    out, L);
}

// Round 4
// 96.734 us; speedup vs baseline: 9.5558x; 1.6347x over previous
//
#include <hip/hip_runtime.h>
#include <math.h>

// ---------------------------------------------------------------------------
// Problem constants: M=30000 nodes, S=8 cells, D=32 channels, DEPTH_LIMIT=10,
// H=64 hidden, L=7M+1 leaves.
// ---------------------------------------------------------------------------

typedef __attribute__((ext_vector_type(8))) short short8;
typedef __attribute__((ext_vector_type(4))) float f32x4;

// Kernel 0: transpose conv_w [d][o][i][k] -> Wt [d][k][i][o], zero feats.
__global__ __launch_bounds__(256) void prep_kernel(
    const float* __restrict__ conv_w, float* __restrict__ Wt,
    float* __restrict__ feats, int total /*81920*/)
{
    int tid = blockIdx.x * 256 + threadIdx.x;
    if (tid < total) {
        int o = tid & 31;
        int i = (tid >> 5) & 31;
        int k = (tid >> 10) & 7;
        int d = tid >> 13;
        Wt[tid] = conv_w[((d * 32 + o) * 32 + i) * 8 + k];
    } else if (tid < total + 32) {
        feats[tid - total] = 0.0f;
    }
}

// Kernel 1: one wave per run of equal parent p in idx_sorted (unchanged).
__global__ __launch_bounds__(64) void conv_scan(
    const float* __restrict__ data, const float* __restrict__ Wt,
    const float* __restrict__ conv_b, const float* __restrict__ depth_weight,
    const int* __restrict__ idx_sorted, const int* __restrict__ depth_sorted,
    const int* __restrict__ node_depth,
    float* __restrict__ pfeats, float* __restrict__ patch, int M)
{
    int t0 = blockIdx.x;
    int p = idx_sorted[t0] >> 3;
    if (t0 > 0 && (idx_sorted[t0 - 1] >> 3) == p) return;  // not a run start

    int n = 1;
    while (t0 + n < M && (idx_sorted[t0 + n] >> 3) == p) n++;

    int cd = node_depth[p];
    const float* __restrict__ W = Wt + cd * 8192;  // [k][i][o]

    __shared__ float blk[8 * 33];
    __shared__ float ubuf[32];

    int l  = threadIdx.x;
    int og = (l & 7) * 4;
    int kg = l >> 3;

    {
        const float4 v = *(const float4*)(data + p * 256 + l * 4);
        int base = kg * 33 + og;
        blk[base + 0] = v.x; blk[base + 1] = v.y;
        blk[base + 2] = v.z; blk[base + 3] = v.w;
    }
    __syncthreads();

    float4 T = {0.f, 0.f, 0.f, 0.f};
    #pragma unroll
    for (int i = 0; i < 32; ++i) {
        float x = blk[kg * 33 + i];
        const float4 w = *(const float4*)(W + (kg * 32 + i) * 32 + og);
        T.x = fmaf(w.x, x, T.x); T.y = fmaf(w.y, x, T.y);
        T.z = fmaf(w.z, x, T.z); T.w = fmaf(w.w, x, T.w);
    }
    #pragma unroll
    for (int m = 8; m <= 32; m <<= 1) {
        T.x += __shfl_xor(T.x, m, 64);
        T.y += __shfl_xor(T.y, m, 64);
        T.z += __shfl_xor(T.z, m, 64);
        T.w += __shfl_xor(T.w, m, 64);
    }

    const float4 bias = *(const float4*)(conv_b + cd * 32 + og);
    float4 pf = {0.f, 0.f, 0.f, 0.f};

    for (int s = 0;; ++s) {
        int   c  = idx_sorted[t0 + s] & 7;
        float dw = depth_weight[depth_sorted[t0 + s]];
        float4 feat = {T.x + bias.x, T.y + bias.y, T.z + bias.z, T.w + bias.w};
        pf.x = fmaf(dw, feat.x, pf.x); pf.y = fmaf(dw, feat.y, pf.y);
        pf.z = fmaf(dw, feat.z, pf.z); pf.w = fmaf(dw, feat.w, pf.w);

        if (s + 1 == n) {
            if (p == 0 && c == 0 && l < 8) {
                *(float4*)(patch + og) = feat;
            }
            break;
        }

        int rb = c * 33 + og;
        float4 oldv = {blk[rb], blk[rb + 1], blk[rb + 2], blk[rb + 3]};
        __syncthreads();
        if (l < 8) {
            blk[rb + 0] = feat.x; blk[rb + 1] = feat.y;
            blk[rb + 2] = feat.z; blk[rb + 3] = feat.w;
            ubuf[og + 0] = feat.x - oldv.x; ubuf[og + 1] = feat.y - oldv.y;
            ubuf[og + 2] = feat.z - oldv.z; ubuf[og + 3] = feat.w - oldv.w;
        }
        __syncthreads();

        float4 acc = {0.f, 0.f, 0.f, 0.f};
        #pragma unroll
        for (int i = 0; i < 32; ++i) {
            float x = ubuf[i];
            const float4 w = *(const float4*)(W + (c * 32 + i) * 32 + og);
            acc.x = fmaf(w.x, x, acc.x); acc.y = fmaf(w.y, x, acc.y);
            acc.z = fmaf(w.z, x, acc.z); acc.w = fmaf(w.w, x, acc.w);
        }
        T.x += acc.x; T.y += acc.y; T.z += acc.z; T.w += acc.w;
    }

    if (l < 8) *(float4*)(pfeats + t0 * 32 + og) = pf;
}

// Kernel 2: sum the per-run partial feats rows (unchanged).
__global__ __launch_bounds__(1024) void reduce_feats(
    const int* __restrict__ idx_sorted, const float* __restrict__ pfeats,
    float* __restrict__ feats, int M)
{
    int ch  = threadIdx.x & 31;
    int sub = threadIdx.x >> 5;
    int base = blockIdx.x * 1000;
    int end  = base + 1000; if (end > M) end = M;

    float a = 0.f;
    for (int t = base + sub; t < end; t += 32) {
        int p = idx_sorted[t] >> 3;
        bool start = (t == 0) || ((idx_sorted[t - 1] >> 3) != p);
        if (start) a += pfeats[t * 32 + ch];
    }
    __shared__ float red[1024];
    red[sub * 32 + ch] = a;
    __syncthreads();
    #pragma unroll
    for (int h = 16; h > 0; h >>= 1) {
        if (sub < h) red[sub * 32 + ch] += red[(sub + h) * 32 + ch];
        __syncthreads();
    }
    if (sub == 0) atomicAdd(&feats[ch], red[ch]);
}

// bf16 round-to-nearest-even helpers for the hi/lo split.
__device__ __forceinline__ unsigned short f2bf_rne(float x) {
    union { float f; unsigned u; } v; v.f = x;
    unsigned r = v.u + 0x7FFFu + ((v.u >> 16) & 1u);
    return (unsigned short)(r >> 16);
}
__device__ __forceinline__ float bf2f(unsigned short h) {
    union { float f; unsigned u; } v; v.u = ((unsigned)h) << 16;
    return v.f;
}

// Inline erf-GELU (A&S 7.1.26, |erf err| <= 1.5e-7).
__device__ __forceinline__ float gelu_erf(float x)
{
    const float s  = x * 0.70710678118654752f;
    const float ax = fabsf(s);
    const float t  = __builtin_amdgcn_rcpf(fmaf(0.3275911f, ax, 1.0f));
    float poly = fmaf(1.061405429f, t, -1.453152027f);
    poly = fmaf(poly, t, 1.421413741f);
    poly = fmaf(poly, t, -0.284496736f);
    poly = fmaf(poly, t, 0.254829592f);
    poly *= t;
    const float e  = __expf(-s * s);
    float er = fmaf(-poly, e, 1.0f);
    er = copysignf(er, s);
    return 0.5f * x * (1.0f + er);
}

// Kernel 3: leaf gather + both MLPs via MFMA.
// Per wave: 64 leaves (4 M-tiles of 16). Layer 1 via mfma_f32_16x16x32_bf16
// with hi/lo split (3 MFMA per tile pair) -> fp32-grade precision.
// A frag: lane holds row = lane&15 (leaf), k = 8*(lane>>4)+i.
// B frag: lane holds col = lane&15 (hidden), k = 8*(lane>>4)+i.
// C: row (leaf) = (lane>>4)*4+reg, col (hidden) = lane&15  [m89-verified].
// Layer 2 + GELU in fp32 VALU, hidden-dim reduced by shfl_xor over bits 0..3.
__global__ __launch_bounds__(256) void mlp_kernel(
    const float* __restrict__ data, const float* __restrict__ feats,
    const float* __restrict__ patch, const int* __restrict__ leaf_idx,
    const float* __restrict__ hf_w1, const float* __restrict__ hf_b1,
    const float* __restrict__ hf_w2, const float* __restrict__ hf_b2,
    const float* __restrict__ hs_w1, const float* __restrict__ hs_b1,
    const float* __restrict__ hs_w2, const float* __restrict__ hs_b2,
    float* __restrict__ out, int L)
{
    int lane = threadIdx.x & 63;
    int base = blockIdx.x * 256 + (threadIdx.x >> 6) * 64;
    if (base >= L) return;
    int n0 = lane & 15;
    int kg = lane >> 4;
    int k0 = kg * 8;

    // feats slice for this lane's k-range
    float fts[8];
    #pragma unroll
    for (int i = 0; i < 8; ++i) fts[i] = feats[k0 + i];

    // B fragments (w1 hi/lo), both MLPs x 4 hidden tiles.  idx q = mlp*4 + t.
    short8 bhi[8], blo[8];
    #pragma unroll
    for (int m = 0; m < 2; ++m) {
        const float* __restrict__ w1 = m ? hs_w1 : hf_w1;
        #pragma unroll
        for (int t = 0; t < 4; ++t) {
            short8 h8, l8;
            #pragma unroll
            for (int i = 0; i < 8; ++i) {
                float w = w1[(k0 + i) * 64 + t * 16 + n0];
                unsigned short hh = f2bf_rne(w);
                h8[i] = (short)hh;
                l8[i] = (short)f2bf_rne(w - bf2f(hh));
            }
            bhi[m * 4 + t] = h8;
            blo[m * 4 + t] = l8;
        }
    }

    // per-lane layer-2 weights (hidden unit t*16+n0) and layer-1 biases
    float w2r[16], b1r[8];
    #pragma unroll
    for (int t = 0; t < 4; ++t) {
        int h = t * 16 + n0;
        w2r[t * 4 + 0] = hf_w2[h * 3 + 0];
        w2r[t * 4 + 1] = hf_w2[h * 3 + 1];
        w2r[t * 4 + 2] = hf_w2[h * 3 + 2];
        w2r[t * 4 + 3] = hs_w2[h];
        b1r[t]     = hf_b1[h];
        b1r[4 + t] = hs_b1[h];
    }
    float b20 = hf_b2[0], b21 = hf_b2[1], b22 = hf_b2[2], b23 = hs_b2[0];

    #pragma unroll
    for (int tm = 0; tm < 4; ++tm) {
        // A fragment: leaf row = base + tm*16 + n0, k-slice k0..k0+7
        int r  = base + tm * 16 + n0;
        int rc = r < L ? r : L - 1;
        int row = leaf_idx[rc];
        const float* __restrict__ src = (row == 0) ? patch : (data + (size_t)row * 32);
        short8 ahi, alo;
        #pragma unroll
        for (int i = 0; i < 8; ++i) {
            float x = src[k0 + i] + fts[i];
            unsigned short hh = f2bf_rne(x);
            ahi[i] = (short)hh;
            alo[i] = (short)f2bf_rne(x - bf2f(hh));
        }

        f32x4 acc[8];
        #pragma unroll
        for (int q = 0; q < 8; ++q) acc[q] = (f32x4){0.f, 0.f, 0.f, 0.f};
        #pragma unroll
        for (int q = 0; q < 8; ++q) {
            acc[q] = __builtin_amdgcn_mfma_f32_16x16x32_bf16(ahi, bhi[q], acc[q], 0, 0, 0);
            acc[q] = __builtin_amdgcn_mfma_f32_16x16x32_bf16(alo, bhi[q], acc[q], 0, 0, 0);
            acc[q] = __builtin_amdgcn_mfma_f32_16x16x32_bf16(ahi, blo[q], acc[q], 0, 0, 0);
        }

        // epilogue: gelu + layer 2 partials (this lane owns hidden t*16+n0,
        // leaves kg*4+reg of this tile)
        float o[4][4];
        #pragma unroll
        for (int g2 = 0; g2 < 4; ++g2) {
            #pragma unroll
            for (int c = 0; c < 4; ++c) o[g2][c] = 0.f;
        }
        #pragma unroll
        for (int t = 0; t < 4; ++t) {
            #pragma unroll
            for (int reg = 0; reg < 4; ++reg) {
                float gf = gelu_erf(acc[t][reg] + b1r[t]);
                float gs = gelu_erf(acc[4 + t][reg] + b1r[4 + t]);
                o[reg][0] = fmaf(gf, w2r[t * 4 + 0], o[reg][0]);
                o[reg][1] = fmaf(gf, w2r[t * 4 + 1], o[reg][1]);
                o[reg][2] = fmaf(gf, w2r[t * 4 + 2], o[reg][2]);
                o[reg][3] = fmaf(gs, w2r[t * 4 + 3], o[reg][3]);
            }
        }
        // reduce hidden dim across lanes 0..15 of each kg group
        #pragma unroll
        for (int mk = 1; mk < 16; mk <<= 1) {
            #pragma unroll
            for (int reg = 0; reg < 4; ++reg) {
                #pragma unroll
                for (int c = 0; c < 4; ++c)
                    o[reg][c] += __shfl_xor(o[reg][c], mk, 64);
            }
        }
        // lanes n0=0..3 write leaf kg*4+n0 of this tile
        if (n0 < 4) {
            int rL = base + tm * 16 + kg * 4 + n0;
            if (rL < L) {
                float s0 = n0 == 0 ? o[0][0] : n0 == 1 ? o[1][0] : n0 == 2 ? o[2][0] : o[3][0];
                float s1 = n0 == 0 ? o[0][1] : n0 == 1 ? o[1][1] : n0 == 2 ? o[2][1] : o[3][1];
                float s2 = n0 == 0 ? o[0][2] : n0 == 1 ? o[1][2] : n0 == 2 ? o[2][2] : o[3][2];
                float s3 = n0 == 0 ? o[0][3] : n0 == 1 ? o[1][3] : n0 == 2 ? o[2][3] : o[3][3];
                float4 res = {s0 + b20, s1 + b21, s2 + b22, s3 + b23};
                *(float4*)(out + (size_t)rL * 4) = res;
            }
        }
    }
}

extern "C" void kernel_launch(void* const* d_in, const int* in_sizes, int n_in,
                              void* d_out, int out_size, void* d_ws, size_t ws_size,
                              hipStream_t stream)
{
    const float* data         = (const float*)d_in[0];
    const float* conv_w       = (const float*)d_in[1];
    const float* conv_b       = (const float*)d_in[2];
    const float* depth_weight = (const float*)d_in[3];
    const float* hf_w1        = (const float*)d_in[4];
    const float* hf_b1        = (const float*)d_in[5];
    const float* hf_w2        = (const float*)d_in[6];
    const float* hf_b2        = (const float*)d_in[7];
    const float* hs_w1        = (const float*)d_in[8];
    const float* hs_b1        = (const float*)d_in[9];
    const float* hs_w2        = (const float*)d_in[10];
    const float* hs_b2        = (const float*)d_in[11];
    const int*   idx_sorted   = (const int*)d_in[12];
    const int*   depth_sorted = (const int*)d_in[13];
    const int*   node_depth   = (const int*)d_in[14];
    const int*   leaf_idx     = (const int*)d_in[15];

    int M = in_sizes[12];   // 30000
    int L = in_sizes[15];   // 210001
    float* out = (float*)d_out;

    // workspace layout (floats): Wt[81920] | feats[32] | patch[32] | pfeats[M*32]
    float* Wt     = (float*)d_ws;
    float* feats  = Wt + 81920;
    float* patch  = feats + 32;
    float* pfeats = patch + 32;
    const int WT = 81920;

    prep_kernel<<<(WT + 32 + 255) / 256, 256, 0, stream>>>(conv_w, Wt, feats, WT);
    conv_scan<<<M, 64, 0, stream>>>(data, Wt, conv_b, depth_weight,
                                    idx_sorted, depth_sorted, node_depth,
                                    pfeats, patch, M);
    reduce_feats<<<(M + 999) / 1000, 1024, 0, stream>>>(idx_sorted, pfeats, feats, M);
    mlp_kernel<<<(L + 255) / 256, 256, 0, stream>>>(data, feats, patch, leaf_idx,
                                                    hf_w1, hf_b1, hf_w2, hf_b2,
                                                    hs_w1, hs_b1, hs_w2, hs_b2,
                                                    out, L);
}